// Round 15
// baseline (238.746 us; speedup 1.0000x reference)
//
#include <hip/hip_runtime.h>
#include <hip/hip_fp16.h>
#include <cfloat>

#define N_NODES 50000
#define N_EDGES 800000
#define NBUK 196          // ceil(N/256) dst-buckets of 256 nodes
#define NAB 512           // A-blocks for the partition
#define EPB 1563          // edges per A-block (512*1563 >= 800000)

typedef _Float16 half8 __attribute__((ext_vector_type(8)));
typedef float f32x4 __attribute__((ext_vector_type(4)));

// All three W[K][BN] f32 -> Wt[BN][K] fp16, one launch
__global__ void wtrans_all(const float* __restrict__ W1, const float* __restrict__ W2,
                           const float* __restrict__ W3, __half* __restrict__ wt1,
                           __half* __restrict__ wt2, __half* __restrict__ wt3) {
    int i = blockIdx.x * blockDim.x + threadIdx.x;
    // W1: 256x128 (32768), W2: 128x128 (16384), W3: 128x64 (8192)
    if (i < 32768) {
        int n = i / 256, k = i % 256;
        wt1[i] = __float2half(W1[k * 128 + n]);
    } else if (i < 32768 + 16384) {
        int j = i - 32768;
        int n = j / 128, k = j % 128;
        wt2[j] = __float2half(W2[k * 128 + n]);
    } else if (i < 32768 + 16384 + 8192) {
        int j = i - 32768 - 16384;
        int n = j / 128, k = j % 128;
        wt3[j] = __float2half(W3[k * 64 + n]);
    }
}

// ============================================================================
// MFMA GEMM: h[N,BN] = x[N,K] @ W (via Wt[BN][K]), fp16 out, f32 acc.
// AF32: A is f32 (converted to fp16 in staging registers) else fp16.
// BM=64, BK=64, 4 waves x 16-row strips. Fused el/er epilogue.
// ============================================================================
template <int BN, int K, bool AF32>
__global__ __launch_bounds__(256)
void gemm_mfma(const void* __restrict__ xin, const __half* __restrict__ wt,
               __half* __restrict__ hh, const float* __restrict__ al,
               const float* __restrict__ ar, float* __restrict__ el,
               float* __restrict__ er) {
    constexpr int BM = 64, BK = 64;
    constexpr int LDA = BK + 8;
    constexpr int NT = BN / 16;
    constexpr int NH = (BN == 128) ? 4 : 1;
    constexpr int TPH = NT / NH;
    __shared__ __align__(16) _Float16 As[BM][LDA];
    __shared__ __align__(16) _Float16 Bs[BN][LDA];

    const __half* xh = (const __half*)xin;
    const float*  xf = (const float*)xin;

    const int t    = threadIdx.x;
    const int lane = t & 63;
    const int w    = t >> 6;
    const int r0   = blockIdx.x * BM;
    const int l15  = lane & 15;
    const int g    = lane >> 4;

    f32x4 acc[NT];
#pragma unroll
    for (int ct = 0; ct < NT; ++ct) acc[ct] = (f32x4){0.f, 0.f, 0.f, 0.f};

    const int arow = t >> 2;
    const int aseg = t & 3;
    const bool aok = (r0 + arow) < N_NODES;
    const int brow = t >> 1;
    const int bseg = t & 1;

    for (int k0 = 0; k0 < K; k0 += BK) {
#pragma unroll
        for (int s = 0; s < 2; ++s) {
            int seg = aseg + 4 * s;
            uint4 v = make_uint4(0, 0, 0, 0);
            if constexpr (AF32) {
                if (aok) {
                    const float* p = xf + (long long)(r0 + arow) * K + k0 + seg * 8;
                    float4 f0 = *reinterpret_cast<const float4*>(p);
                    float4 f1 = *reinterpret_cast<const float4*>(p + 4);
                    union { uint4 u; __half2 h[4]; } cv;
                    cv.h[0] = __floats2half2_rn(f0.x, f0.y);
                    cv.h[1] = __floats2half2_rn(f0.z, f0.w);
                    cv.h[2] = __floats2half2_rn(f1.x, f1.y);
                    cv.h[3] = __floats2half2_rn(f1.z, f1.w);
                    v = cv.u;
                }
            } else {
                if (aok) v = *reinterpret_cast<const uint4*>(xh + (long long)(r0 + arow) * K + k0 + seg * 8);
            }
            *reinterpret_cast<uint4*>(&As[arow][seg * 8]) = v;
        }
        if (brow < BN) {
#pragma unroll
            for (int s = 0; s < 4; ++s) {
                int seg = bseg + 2 * s;
                uint4 v = *reinterpret_cast<const uint4*>(wt + (long long)brow * K + k0 + seg * 8);
                *reinterpret_cast<uint4*>(&Bs[brow][seg * 8]) = v;
            }
        }
        __syncthreads();

#pragma unroll
        for (int kb = 0; kb < 2; ++kb) {
            half8 a = *reinterpret_cast<const half8*>(&As[w * 16 + l15][kb * 32 + g * 8]);
#pragma unroll
            for (int ct = 0; ct < NT; ++ct) {
                half8 b = *reinterpret_cast<const half8*>(&Bs[ct * 16 + l15][kb * 32 + g * 8]);
                acc[ct] = __builtin_amdgcn_mfma_f32_16x16x32_f16(a, b, acc[ct], 0, 0, 0);
            }
        }
        __syncthreads();
    }

    float alv[NT], arv[NT];
#pragma unroll
    for (int ct = 0; ct < NT; ++ct) {
        alv[ct] = al[ct * 16 + l15];
        arv[ct] = ar[ct * 16 + l15];
    }

    float pel[NH][4], per_[NH][4];
#pragma unroll
    for (int hd = 0; hd < NH; ++hd)
#pragma unroll
        for (int b = 0; b < 4; ++b) { pel[hd][b] = 0.f; per_[hd][b] = 0.f; }

#pragma unroll
    for (int ct = 0; ct < NT; ++ct) {
        int hd = ct / TPH;
#pragma unroll
        for (int b = 0; b < 4; ++b) {
            pel[hd][b] += acc[ct][b] * alv[ct];
            per_[hd][b] += acc[ct][b] * arv[ct];
        }
    }
#pragma unroll
    for (int off = 1; off < 16; off <<= 1) {
#pragma unroll
        for (int hd = 0; hd < NH; ++hd)
#pragma unroll
            for (int b = 0; b < 4; ++b) {
                pel[hd][b] += __shfl_xor(pel[hd][b], off);
                per_[hd][b] += __shfl_xor(per_[hd][b], off);
            }
    }

#pragma unroll
    for (int b = 0; b < 4; ++b) {
        int row = r0 + w * 16 + g * 4 + b;
        if (row >= N_NODES) continue;
#pragma unroll
        for (int ct = 0; ct < NT; ++ct)
            hh[(long long)row * BN + ct * 16 + l15] = __float2half(acc[ct][b]);
        if (l15 == 0) {
#pragma unroll
            for (int hd = 0; hd < NH; ++hd) {
                el[row * NH + hd] = pel[hd][b];
                er[row * NH + hd] = per_[hd][b];
            }
        }
    }
}

// ============================================================================
// CSR build: node hist -> scan row_ptr -> contention-free 2-level partition
// ============================================================================
__global__ void zero_counts(int* __restrict__ counts) {
    int i = blockIdx.x * blockDim.x + threadIdx.x;
    if (i < N_NODES) counts[i] = 0;
}

__global__ void hist_kernel(const int* __restrict__ dst, int* __restrict__ counts) {
    int e = blockIdx.x * blockDim.x + threadIdx.x;
    if (e < N_EDGES) atomicAdd(counts + dst[e], 1);
}

__global__ __launch_bounds__(1024)
void scan_local(const int* __restrict__ counts, int* __restrict__ row_ptr,
                int* __restrict__ bsum) {
    __shared__ int wsums[16];
    const int tid = threadIdx.x, lane = tid & 63, wid = tid >> 6;
    const int i = blockIdx.x * 1024 + tid;
    int v = (i < N_NODES) ? counts[i] : 0;
    int incl = v;
#pragma unroll
    for (int off = 1; off < 64; off <<= 1) {
        int t = __shfl_up(incl, off);
        if (lane >= off) incl += t;
    }
    if (lane == 63) wsums[wid] = incl;
    __syncthreads();
    if (wid == 0) {
        int ws = (lane < 16) ? wsums[lane] : 0;
#pragma unroll
        for (int off = 1; off < 16; off <<= 1) {
            int t = __shfl_up(ws, off);
            if (lane >= off) ws += t;
        }
        if (lane < 16) wsums[lane] = ws;
        if (lane == 15) bsum[blockIdx.x] = ws;
    }
    __syncthreads();
    int woff = (wid > 0) ? wsums[wid - 1] : 0;
    if (i < N_NODES) row_ptr[i] = woff + incl - v;
}

__global__ void scan_bsums(int* __restrict__ bsum, int* __restrict__ row_ptr, int nb) {
    const int lane = threadIdx.x;
    int v = (lane < nb) ? bsum[lane] : 0;
    int incl = v;
#pragma unroll
    for (int off = 1; off < 64; off <<= 1) {
        int t = __shfl_up(incl, off);
        if (lane >= off) incl += t;
    }
    if (lane < nb) bsum[lane] = incl - v;
    if (lane == 63) row_ptr[N_NODES] = incl;
}

__global__ void scan_add(int* __restrict__ row_ptr, const int* __restrict__ bsum) {
    int i = blockIdx.x * blockDim.x + threadIdx.x;
    if (i < N_NODES) row_ptr[i] += bsum[i >> 10];
}

// P1: per (A-block, bucket) histogram via LDS
__global__ __launch_bounds__(256)
void part_hist(const int* __restrict__ dst, int* __restrict__ pbh) {
    __shared__ int cnt[NBUK];
    for (int i = threadIdx.x; i < NBUK; i += 256) cnt[i] = 0;
    __syncthreads();
    const int e0 = blockIdx.x * EPB, e1 = min(N_EDGES, e0 + EPB);
    for (int e = e0 + threadIdx.x; e < e1; e += 256)
        atomicAdd(&cnt[dst[e] >> 8], 1);
    __syncthreads();
    for (int i = threadIdx.x; i < NBUK; i += 256)
        pbh[i * NAB + blockIdx.x] = cnt[i];
}

// P2: per-bucket exclusive scan over NAB=512 A-block counts (8-wave block scan)
__global__ __launch_bounds__(512)
void part_scan(const int* __restrict__ row_ptr, int* __restrict__ pbh) {
    __shared__ int wsums[8];
    const int b = blockIdx.x, t = threadIdx.x, lane = t & 63, wid = t >> 6;
    int v = pbh[b * NAB + t];
    int incl = v;
#pragma unroll
    for (int off = 1; off < 64; off <<= 1) {
        int s = __shfl_up(incl, off);
        if (lane >= off) incl += s;
    }
    if (lane == 63) wsums[wid] = incl;
    __syncthreads();
    if (wid == 0) {
        int ws = (lane < 8) ? wsums[lane] : 0;
#pragma unroll
        for (int off = 1; off < 8; off <<= 1) {
            int s = __shfl_up(ws, off);
            if (lane >= off) ws += s;
        }
        if (lane < 8) wsums[lane] = ws;
    }
    __syncthreads();
    int woff = (wid > 0) ? wsums[wid - 1] : 0;
    pbh[b * NAB + t] = row_ptr[b * 256] + woff + incl - v;
}

// P3: scatter into bucket bins — LDS cursors only (no global atomics)
__global__ __launch_bounds__(256)
void part_scatter(const int* __restrict__ src, const int* __restrict__ dst,
                  const int* __restrict__ pbh, unsigned* __restrict__ binned) {
    __shared__ int cur[NBUK];
    for (int i = threadIdx.x; i < NBUK; i += 256)
        cur[i] = pbh[i * NAB + blockIdx.x];
    __syncthreads();
    const int e0 = blockIdx.x * EPB, e1 = min(N_EDGES, e0 + EPB);
    for (int e = e0 + threadIdx.x; e < e1; e += 256) {
        int d = dst[e];
        int pos = atomicAdd(&cur[d >> 8], 1);
        binned[pos] = ((unsigned)src[e] << 8) | (unsigned)(d & 255);
    }
}

// P4: finalize within each bucket's dense 16KB window (L2-resident)
__global__ __launch_bounds__(256)
void part_fin(const int* __restrict__ row_ptr, const unsigned* __restrict__ binned,
              int* __restrict__ sorted_src) {
    __shared__ int cur[256];
    const int b  = blockIdx.x;
    const int n0 = b * 256;
    const int n1 = min(N_NODES, n0 + 256);
    const int t  = threadIdx.x;
    if (n0 + t < n1) cur[t] = row_ptr[n0 + t];
    __syncthreads();
    const int e0 = row_ptr[n0], e1 = row_ptr[n1];
    for (int e = e0 + t; e < e1; e += 256) {
        unsigned p = binned[e];
        int pos = atomicAdd(&cur[p & 255u], 1);
        sorted_src[pos] = (int)(p >> 8);
    }
}

// ============================================================================
// Wave-per-node aggregate, 4 heads (F=128), fp16 h, no max pass, 8 edges/iter.
// Octet o = lane>>3 owns edge slot; lane covers cols (lane&7)*16 via 2x16B
// loads (2x memory ILP). Weight owner: lane l computes head l>>4 for edges
// ee=(l&15)+16k; reader (head hr=(lane&7)>>1) pulls w from lane
// (8*(it&1)+o)|(hr<<4), register it>>1 (compile-time under full unroll).
// Merge octets via shfl_xor(8/16/32). Output fp16 (feeds next GEMM).
// ============================================================================
__global__ __launch_bounds__(256)
void gat_agg_h4(const int* __restrict__ row_ptr, const int* __restrict__ sorted_src,
                const float* __restrict__ el, const float* __restrict__ er,
                const __half* __restrict__ hh, const float* __restrict__ bias,
                __half* __restrict__ out) {
    const uint4* hh16 = reinterpret_cast<const uint4*>(hh);   // row = 16 x 16B
    const int lane = threadIdx.x & 63;
    const int wid  = threadIdx.x >> 6;
    const int n    = blockIdx.x * 4 + wid;
    if (n >= N_NODES) return;

    const int start = row_ptr[n];
    const int deg   = row_ptr[n + 1] - start;

    const float4 ern = *reinterpret_cast<const float4*>(er + n * 4);

    // owner role
    const int ho = lane >> 4;
    const float eoa = (ho & 2) ? ern.z : ern.x;
    const float eob = (ho & 2) ? ern.w : ern.y;
    const float ero = (ho & 1) ? eob : eoa;

    // reader role
    const int o   = lane >> 3;          // edge slot in octet
    const int cg  = lane & 7;           // col group: cols cg*16..cg*16+15
    const int hr  = cg >> 1;            // head of those cols
    const int hsh = hr << 4;

    float a[16];
#pragma unroll
    for (int i = 0; i < 16; ++i) a[i] = 0.f;
    float ssum = 0.f;

    for (int base = 0; base < deg; base += 64) {
        int cnt = min(64, deg - base);
        int sr = 0;
        if (lane < cnt) sr = sorted_src[start + base + lane];

        float w[4];
#pragma unroll
        for (int k = 0; k < 4; ++k) {
            int ee = (lane & 15) + 16 * k;
            int sk = __shfl(sr, ee);
            float v = el[sk * 4 + ho] + ero;
            v = (v >= 0.f) ? v : 0.2f * v;
            w[k] = (ee < cnt) ? __expf(v) : 0.f;
        }

        int octs = (cnt + 7) >> 3;
#pragma unroll
        for (int it = 0; it < 8; ++it) {
            if (it < octs) {
                int e0 = 8 * it + o;
                int   se = __shfl(sr, e0);
                float we = __shfl(w[it >> 1], (8 * (it & 1) + o) | hsh);
                uint4 r0 = hh16[(long long)se * 16 + cg * 2];
                uint4 r1 = hh16[(long long)se * 16 + cg * 2 + 1];
                union { uint4 u; __half2 h[4]; } c0, c1;
                c0.u = r0; c1.u = r1;
#pragma unroll
                for (int j = 0; j < 4; ++j) {
                    float2 v0 = __half22float2(c0.h[j]);
                    float2 v1 = __half22float2(c1.h[j]);
                    a[2 * j + 0] += we * v0.x;
                    a[2 * j + 1] += we * v0.y;
                    a[8 + 2 * j + 0] += we * v1.x;
                    a[8 + 2 * j + 1] += we * v1.y;
                }
                ssum += we;
            }
        }
    }

    // merge octets (bits 3, 4, 5)
#pragma unroll
    for (int i = 0; i < 16; ++i) {
        a[i] += __shfl_xor(a[i], 8);
        a[i] += __shfl_xor(a[i], 16);
        a[i] += __shfl_xor(a[i], 32);
    }
    ssum += __shfl_xor(ssum, 8);
    ssum += __shfl_xor(ssum, 16);
    ssum += __shfl_xor(ssum, 32);

    if (lane < 8) {
        float inv = (ssum > 0.f) ? 1.f / ssum : 0.f;
        int c0 = cg * 16;
        union { uint4 u; __half2 h[4]; } pk0, pk1;
#pragma unroll
        for (int j = 0; j < 4; ++j) {
            float2 bj0 = *reinterpret_cast<const float2*>(bias + c0 + 2 * j);
            float2 bj1 = *reinterpret_cast<const float2*>(bias + c0 + 8 + 2 * j);
            float oa = fmaxf(a[2 * j + 0] * inv + bj0.x, 0.f);
            float ob = fmaxf(a[2 * j + 1] * inv + bj0.y, 0.f);
            float oc = fmaxf(a[8 + 2 * j + 0] * inv + bj1.x, 0.f);
            float od = fmaxf(a[8 + 2 * j + 1] * inv + bj1.y, 0.f);
            pk0.h[j] = __floats2half2_rn(oa, ob);
            pk1.h[j] = __floats2half2_rn(oc, od);
        }
        *reinterpret_cast<uint4*>(out + (long long)n * 128 + c0)     = pk0.u;
        *reinterpret_cast<uint4*>(out + (long long)n * 128 + c0 + 8) = pk1.u;
    }
}

// ---- single-head (F=64), fp16 h, 8 edges/iter (16B loads), f32 out ----
__global__ __launch_bounds__(256)
void gat_agg_h1(const int* __restrict__ row_ptr, const int* __restrict__ sorted_src,
                const float* __restrict__ el, const float* __restrict__ er,
                const __half* __restrict__ hh, const float* __restrict__ bias,
                float* __restrict__ out) {
    const uint4* hh16 = reinterpret_cast<const uint4*>(hh);   // row = 8 x 16B
    const int lane = threadIdx.x & 63;
    const int wid  = threadIdx.x >> 6;
    const int n    = blockIdx.x * 4 + wid;
    if (n >= N_NODES) return;

    const int start = row_ptr[n];
    const int deg   = row_ptr[n + 1] - start;
    const float ern = er[n];

    const int q  = lane >> 3;           // edge slot 0..7
    const int cg = lane & 7;            // cols cg*8..cg*8+7

    float a[8];
#pragma unroll
    for (int i = 0; i < 8; ++i) a[i] = 0.f;
    float ssum = 0.f;

    for (int base = 0; base < deg; base += 64) {
        int cnt = min(64, deg - base);
        int sr = 0;
        float w = 0.f;
        if (lane < cnt) {
            sr = sorted_src[start + base + lane];
            float v = el[sr] + ern;
            v = (v >= 0.f) ? v : 0.2f * v;
            w = __expf(v);
        }
        int octs = (cnt + 7) >> 3;
#pragma unroll 2
        for (int it = 0; it < octs; ++it) {
            int e0 = 8 * it + q;
            int   se = __shfl(sr, e0);
            float we = __shfl(w, e0);
            uint4 raw = hh16[(long long)se * 8 + cg];
            union { uint4 u; __half2 h[4]; } cv; cv.u = raw;
            float2 v0 = __half22float2(cv.h[0]);
            float2 v1 = __half22float2(cv.h[1]);
            float2 v2 = __half22float2(cv.h[2]);
            float2 v3 = __half22float2(cv.h[3]);
            a[0] += we * v0.x; a[1] += we * v0.y;
            a[2] += we * v1.x; a[3] += we * v1.y;
            a[4] += we * v2.x; a[5] += we * v2.y;
            a[6] += we * v3.x; a[7] += we * v3.y;
            ssum += we;
        }
    }

#pragma unroll
    for (int i = 0; i < 8; ++i) {
        a[i] += __shfl_xor(a[i], 8);
        a[i] += __shfl_xor(a[i], 16);
        a[i] += __shfl_xor(a[i], 32);
    }
    ssum += __shfl_xor(ssum, 8);
    ssum += __shfl_xor(ssum, 16);
    ssum += __shfl_xor(ssum, 32);

    if (lane < 8) {
        float inv = (ssum > 0.f) ? 1.f / ssum : 0.f;
        int c0 = cg * 8;
        float4 b0 = *reinterpret_cast<const float4*>(bias + c0);
        float4 b1 = *reinterpret_cast<const float4*>(bias + c0 + 4);
        float4 oA = make_float4(a[0] * inv + b0.x, a[1] * inv + b0.y,
                                a[2] * inv + b0.z, a[3] * inv + b0.w);
        float4 oB = make_float4(a[4] * inv + b1.x, a[5] * inv + b1.y,
                                a[6] * inv + b1.z, a[7] * inv + b1.w);
        *reinterpret_cast<float4*>(out + (long long)n * 64 + c0)     = oA;
        *reinterpret_cast<float4*>(out + (long long)n * 64 + c0 + 4) = oB;
    }
}

extern "C" void kernel_launch(void* const* d_in, const int* in_sizes, int n_in,
                              void* d_out, int out_size, void* d_ws, size_t ws_size,
                              hipStream_t stream) {
    const float* feat = (const float*)d_in[0];
    const int*   src  = (const int*)d_in[1];
    const int*   dst  = (const int*)d_in[2];
    const float* W1  = (const float*)d_in[3];
    const float* al1 = (const float*)d_in[4];
    const float* ar1 = (const float*)d_in[5];
    const float* b1  = (const float*)d_in[6];
    const float* W2  = (const float*)d_in[7];
    const float* al2 = (const float*)d_in[8];
    const float* ar2 = (const float*)d_in[9];
    const float* b2  = (const float*)d_in[10];
    const float* W3  = (const float*)d_in[11];
    const float* al3 = (const float*)d_in[12];
    const float* ar3 = (const float*)d_in[13];
    const float* b3  = (const float*)d_in[14];

    // workspace carve-up (offsets in f32 units on the base pointer)
    float* ws = (float*)d_ws;
    __half* xh2 = (__half*)ws;                              // N*128 halves = N*64 f32
    __half* hh  = (__half*)(ws + (long long)N_NODES * 64);  // N*128 halves
    float* el   = ws + (long long)N_NODES * 128;            // N*4
    float* er   = el + (long long)N_NODES * 4;              // N*4
    __half* wt1 = (__half*)(er + (long long)N_NODES * 4);   // 32768 halves
    __half* wt2 = wt1 + 32768;                              // 16384 halves
    __half* wt3 = wt2 + 16384;                              // 8192 halves
    int* counts     = (int*)(wt3 + 8192);                   // N
    int* row_ptr    = counts  + N_NODES;                    // N+1
    int* pbh        = row_ptr + N_NODES + 1;                // NBUK*NAB
    int* bsum       = pbh + NBUK * NAB;                     // 64
    int* sorted_src = bsum + 64;                            // E
    unsigned* binned = (unsigned*)(sorted_src + N_EDGES);   // E

    // ---- CSR build: hist -> scan -> 2-level partition ----
    const int SB = (N_NODES + 1023) / 1024;   // 49
    zero_counts<<<(N_NODES + 255) / 256, 256, 0, stream>>>(counts);
    hist_kernel<<<(N_EDGES + 255) / 256, 256, 0, stream>>>(dst, counts);
    scan_local<<<SB, 1024, 0, stream>>>(counts, row_ptr, bsum);
    scan_bsums<<<1, 64, 0, stream>>>(bsum, row_ptr, SB);
    scan_add<<<(N_NODES + 255) / 256, 256, 0, stream>>>(row_ptr, bsum);
    part_hist<<<NAB, 256, 0, stream>>>(dst, pbh);
    part_scan<<<NBUK, 512, 0, stream>>>(row_ptr, pbh);
    part_scatter<<<NAB, 256, 0, stream>>>(src, dst, pbh, binned);
    part_fin<<<NBUK, 256, 0, stream>>>(row_ptr, binned, sorted_src);

    // all weight transposes in one launch
    wtrans_all<<<(57344 + 255) / 256, 256, 0, stream>>>(W1, W2, W3, wt1, wt2, wt3);

    const int gblocks = (N_NODES + 63) / 64;   // 782
    const int nblocks = (N_NODES + 3) / 4;

    // ---- layer 1: 256 -> 4x32, relu (A read directly as f32) ----
    gemm_mfma<128, 256, true><<<gblocks, 256, 0, stream>>>(feat, wt1, hh, al1, ar1, el, er);
    gat_agg_h4<<<nblocks, 256, 0, stream>>>(row_ptr, sorted_src, el, er, hh, b1, xh2);

    // ---- layer 2: 128 -> 4x32, relu ----
    gemm_mfma<128, 128, false><<<gblocks, 256, 0, stream>>>(xh2, wt2, hh, al2, ar2, el, er);
    gat_agg_h4<<<nblocks, 256, 0, stream>>>(row_ptr, sorted_src, el, er, hh, b2, xh2);

    // ---- layer 3: 128 -> 1x64, no relu, f32 to d_out ----
    gemm_mfma<64, 128, false><<<gblocks, 256, 0, stream>>>(xh2, wt3, hh, al3, ar3, el, er);
    gat_agg_h1<<<nblocks, 256, 0, stream>>>(row_ptr, sorted_src, el, er, hh, b3, (float*)d_out);
}

// Round 16
// 230.716 us; speedup vs baseline: 1.0348x; 1.0348x over previous
//
#include <hip/hip_runtime.h>
#include <hip/hip_fp16.h>
#include <cfloat>

#define N_NODES 50000
#define N_EDGES 800000
#define NBUK 196          // ceil(N/256) dst-buckets of 256 nodes
#define NAB 512           // A-blocks for the partition
#define EPB 1563          // edges per A-block (512*1563 >= 800000)

typedef _Float16 half8 __attribute__((ext_vector_type(8)));
typedef float f32x4 __attribute__((ext_vector_type(4)));

// All three W[K][BN] f32 -> Wt[BN][K] fp16, one launch
__global__ void wtrans_all(const float* __restrict__ W1, const float* __restrict__ W2,
                           const float* __restrict__ W3, __half* __restrict__ wt1,
                           __half* __restrict__ wt2, __half* __restrict__ wt3) {
    int i = blockIdx.x * blockDim.x + threadIdx.x;
    // W1: 256x128 (32768), W2: 128x128 (16384), W3: 128x64 (8192)
    if (i < 32768) {
        int n = i / 256, k = i % 256;
        wt1[i] = __float2half(W1[k * 128 + n]);
    } else if (i < 32768 + 16384) {
        int j = i - 32768;
        int n = j / 128, k = j % 128;
        wt2[j] = __float2half(W2[k * 128 + n]);
    } else if (i < 32768 + 16384 + 8192) {
        int j = i - 32768 - 16384;
        int n = j / 128, k = j % 128;
        wt3[j] = __float2half(W3[k * 64 + n]);
    }
}

// ============================================================================
// MFMA GEMM: h[N,BN] = x[N,K] @ W (via Wt[BN][K]), fp16 out, f32 acc.
// AF32: A is f32 (converted to fp16 in staging registers) else fp16.
// BM=64, BK=64, 4 waves x 16-row strips. Fused el/er epilogue.
// ============================================================================
template <int BN, int K, bool AF32>
__global__ __launch_bounds__(256)
void gemm_mfma(const void* __restrict__ xin, const __half* __restrict__ wt,
               __half* __restrict__ hh, const float* __restrict__ al,
               const float* __restrict__ ar, float* __restrict__ el,
               float* __restrict__ er) {
    constexpr int BM = 64, BK = 64;
    constexpr int LDA = BK + 8;
    constexpr int NT = BN / 16;
    constexpr int NH = (BN == 128) ? 4 : 1;
    constexpr int TPH = NT / NH;
    __shared__ __align__(16) _Float16 As[BM][LDA];
    __shared__ __align__(16) _Float16 Bs[BN][LDA];

    const __half* xh = (const __half*)xin;
    const float*  xf = (const float*)xin;

    const int t    = threadIdx.x;
    const int lane = t & 63;
    const int w    = t >> 6;
    const int r0   = blockIdx.x * BM;
    const int l15  = lane & 15;
    const int g    = lane >> 4;

    f32x4 acc[NT];
#pragma unroll
    for (int ct = 0; ct < NT; ++ct) acc[ct] = (f32x4){0.f, 0.f, 0.f, 0.f};

    const int arow = t >> 2;
    const int aseg = t & 3;
    const bool aok = (r0 + arow) < N_NODES;
    const int brow = t >> 1;
    const int bseg = t & 1;

    for (int k0 = 0; k0 < K; k0 += BK) {
#pragma unroll
        for (int s = 0; s < 2; ++s) {
            int seg = aseg + 4 * s;
            uint4 v = make_uint4(0, 0, 0, 0);
            if constexpr (AF32) {
                if (aok) {
                    const float* p = xf + (long long)(r0 + arow) * K + k0 + seg * 8;
                    float4 f0 = *reinterpret_cast<const float4*>(p);
                    float4 f1 = *reinterpret_cast<const float4*>(p + 4);
                    union { uint4 u; __half2 h[4]; } cv;
                    cv.h[0] = __floats2half2_rn(f0.x, f0.y);
                    cv.h[1] = __floats2half2_rn(f0.z, f0.w);
                    cv.h[2] = __floats2half2_rn(f1.x, f1.y);
                    cv.h[3] = __floats2half2_rn(f1.z, f1.w);
                    v = cv.u;
                }
            } else {
                if (aok) v = *reinterpret_cast<const uint4*>(xh + (long long)(r0 + arow) * K + k0 + seg * 8);
            }
            *reinterpret_cast<uint4*>(&As[arow][seg * 8]) = v;
        }
        if (brow < BN) {
#pragma unroll
            for (int s = 0; s < 4; ++s) {
                int seg = bseg + 2 * s;
                uint4 v = *reinterpret_cast<const uint4*>(wt + (long long)brow * K + k0 + seg * 8);
                *reinterpret_cast<uint4*>(&Bs[brow][seg * 8]) = v;
            }
        }
        __syncthreads();

#pragma unroll
        for (int kb = 0; kb < 2; ++kb) {
            half8 a = *reinterpret_cast<const half8*>(&As[w * 16 + l15][kb * 32 + g * 8]);
#pragma unroll
            for (int ct = 0; ct < NT; ++ct) {
                half8 b = *reinterpret_cast<const half8*>(&Bs[ct * 16 + l15][kb * 32 + g * 8]);
                acc[ct] = __builtin_amdgcn_mfma_f32_16x16x32_f16(a, b, acc[ct], 0, 0, 0);
            }
        }
        __syncthreads();
    }

    float alv[NT], arv[NT];
#pragma unroll
    for (int ct = 0; ct < NT; ++ct) {
        alv[ct] = al[ct * 16 + l15];
        arv[ct] = ar[ct * 16 + l15];
    }

    float pel[NH][4], per_[NH][4];
#pragma unroll
    for (int hd = 0; hd < NH; ++hd)
#pragma unroll
        for (int b = 0; b < 4; ++b) { pel[hd][b] = 0.f; per_[hd][b] = 0.f; }

#pragma unroll
    for (int ct = 0; ct < NT; ++ct) {
        int hd = ct / TPH;
#pragma unroll
        for (int b = 0; b < 4; ++b) {
            pel[hd][b] += acc[ct][b] * alv[ct];
            per_[hd][b] += acc[ct][b] * arv[ct];
        }
    }
#pragma unroll
    for (int off = 1; off < 16; off <<= 1) {
#pragma unroll
        for (int hd = 0; hd < NH; ++hd)
#pragma unroll
            for (int b = 0; b < 4; ++b) {
                pel[hd][b] += __shfl_xor(pel[hd][b], off);
                per_[hd][b] += __shfl_xor(per_[hd][b], off);
            }
    }

#pragma unroll
    for (int b = 0; b < 4; ++b) {
        int row = r0 + w * 16 + g * 4 + b;
        if (row >= N_NODES) continue;
#pragma unroll
        for (int ct = 0; ct < NT; ++ct)
            hh[(long long)row * BN + ct * 16 + l15] = __float2half(acc[ct][b]);
        if (l15 == 0) {
#pragma unroll
            for (int hd = 0; hd < NH; ++hd) {
                el[row * NH + hd] = pel[hd][b];
                er[row * NH + hd] = per_[hd][b];
            }
        }
    }
}

// ============================================================================
// CSR build: node hist -> scan row_ptr -> contention-free 2-level partition
// ============================================================================
__global__ void zero_counts(int* __restrict__ counts) {
    int i = blockIdx.x * blockDim.x + threadIdx.x;
    if (i < N_NODES) counts[i] = 0;
}

__global__ void hist_kernel(const int* __restrict__ dst, int* __restrict__ counts) {
    int e = blockIdx.x * blockDim.x + threadIdx.x;
    if (e < N_EDGES) atomicAdd(counts + dst[e], 1);
}

__global__ __launch_bounds__(1024)
void scan_local(const int* __restrict__ counts, int* __restrict__ row_ptr,
                int* __restrict__ bsum) {
    __shared__ int wsums[16];
    const int tid = threadIdx.x, lane = tid & 63, wid = tid >> 6;
    const int i = blockIdx.x * 1024 + tid;
    int v = (i < N_NODES) ? counts[i] : 0;
    int incl = v;
#pragma unroll
    for (int off = 1; off < 64; off <<= 1) {
        int t = __shfl_up(incl, off);
        if (lane >= off) incl += t;
    }
    if (lane == 63) wsums[wid] = incl;
    __syncthreads();
    if (wid == 0) {
        int ws = (lane < 16) ? wsums[lane] : 0;
#pragma unroll
        for (int off = 1; off < 16; off <<= 1) {
            int t = __shfl_up(ws, off);
            if (lane >= off) ws += t;
        }
        if (lane < 16) wsums[lane] = ws;
        if (lane == 15) bsum[blockIdx.x] = ws;
    }
    __syncthreads();
    int woff = (wid > 0) ? wsums[wid - 1] : 0;
    if (i < N_NODES) row_ptr[i] = woff + incl - v;
}

__global__ void scan_bsums(int* __restrict__ bsum, int* __restrict__ row_ptr, int nb) {
    const int lane = threadIdx.x;
    int v = (lane < nb) ? bsum[lane] : 0;
    int incl = v;
#pragma unroll
    for (int off = 1; off < 64; off <<= 1) {
        int t = __shfl_up(incl, off);
        if (lane >= off) incl += t;
    }
    if (lane < nb) bsum[lane] = incl - v;
    if (lane == 63) row_ptr[N_NODES] = incl;
}

__global__ void scan_add(int* __restrict__ row_ptr, const int* __restrict__ bsum) {
    int i = blockIdx.x * blockDim.x + threadIdx.x;
    if (i < N_NODES) row_ptr[i] += bsum[i >> 10];
}

// P1: per (A-block, bucket) histogram via LDS
__global__ __launch_bounds__(256)
void part_hist(const int* __restrict__ dst, int* __restrict__ pbh) {
    __shared__ int cnt[NBUK];
    for (int i = threadIdx.x; i < NBUK; i += 256) cnt[i] = 0;
    __syncthreads();
    const int e0 = blockIdx.x * EPB, e1 = min(N_EDGES, e0 + EPB);
    for (int e = e0 + threadIdx.x; e < e1; e += 256)
        atomicAdd(&cnt[dst[e] >> 8], 1);
    __syncthreads();
    for (int i = threadIdx.x; i < NBUK; i += 256)
        pbh[i * NAB + blockIdx.x] = cnt[i];
}

// P2: per-bucket exclusive scan over NAB=512 A-block counts (8-wave block scan)
__global__ __launch_bounds__(512)
void part_scan(const int* __restrict__ row_ptr, int* __restrict__ pbh) {
    __shared__ int wsums[8];
    const int b = blockIdx.x, t = threadIdx.x, lane = t & 63, wid = t >> 6;
    int v = pbh[b * NAB + t];
    int incl = v;
#pragma unroll
    for (int off = 1; off < 64; off <<= 1) {
        int s = __shfl_up(incl, off);
        if (lane >= off) incl += s;
    }
    if (lane == 63) wsums[wid] = incl;
    __syncthreads();
    if (wid == 0) {
        int ws = (lane < 8) ? wsums[lane] : 0;
#pragma unroll
        for (int off = 1; off < 8; off <<= 1) {
            int s = __shfl_up(ws, off);
            if (lane >= off) ws += s;
        }
        if (lane < 8) wsums[lane] = ws;
    }
    __syncthreads();
    int woff = (wid > 0) ? wsums[wid - 1] : 0;
    pbh[b * NAB + t] = row_ptr[b * 256] + woff + incl - v;
}

// P3: scatter into bucket bins — LDS cursors only (no global atomics)
__global__ __launch_bounds__(256)
void part_scatter(const int* __restrict__ src, const int* __restrict__ dst,
                  const int* __restrict__ pbh, unsigned* __restrict__ binned) {
    __shared__ int cur[NBUK];
    for (int i = threadIdx.x; i < NBUK; i += 256)
        cur[i] = pbh[i * NAB + blockIdx.x];
    __syncthreads();
    const int e0 = blockIdx.x * EPB, e1 = min(N_EDGES, e0 + EPB);
    for (int e = e0 + threadIdx.x; e < e1; e += 256) {
        int d = dst[e];
        int pos = atomicAdd(&cur[d >> 8], 1);
        binned[pos] = ((unsigned)src[e] << 8) | (unsigned)(d & 255);
    }
}

// P4: finalize within each bucket's dense 16KB window (L2-resident)
__global__ __launch_bounds__(256)
void part_fin(const int* __restrict__ row_ptr, const unsigned* __restrict__ binned,
              int* __restrict__ sorted_src) {
    __shared__ int cur[256];
    const int b  = blockIdx.x;
    const int n0 = b * 256;
    const int n1 = min(N_NODES, n0 + 256);
    const int t  = threadIdx.x;
    if (n0 + t < n1) cur[t] = row_ptr[n0 + t];
    __syncthreads();
    const int e0 = row_ptr[n0], e1 = row_ptr[n1];
    for (int e = e0 + t; e < e1; e += 256) {
        unsigned p = binned[e];
        int pos = atomicAdd(&cur[p & 255u], 1);
        sorted_src[pos] = (int)(p >> 8);
    }
}

// ============================================================================
// Wave-per-node aggregate, 4 heads (F=128), fp16 h, no max pass, 4 edges/iter.
// (R14's measured-best form: quarter q owns edge slot, lane covers 8 cols via
// one 16B load; weight owner lane l computes head l>>4 for edges ee=(l&15)+16k;
// reader head hr=(lane&15)>>2 pulls w from lane (4it+q)|(hr<<4), register k.)
// ============================================================================
__global__ __launch_bounds__(256)
void gat_agg_h4(const int* __restrict__ row_ptr, const int* __restrict__ sorted_src,
                const float* __restrict__ el, const float* __restrict__ er,
                const __half* __restrict__ hh, const float* __restrict__ bias,
                __half* __restrict__ out) {
    const uint4* hh16 = reinterpret_cast<const uint4*>(hh);   // row = 16 x 16B
    const int lane = threadIdx.x & 63;
    const int wid  = threadIdx.x >> 6;
    const int n    = blockIdx.x * 4 + wid;
    if (n >= N_NODES) return;

    const int start = row_ptr[n];
    const int deg   = row_ptr[n + 1] - start;

    const float4 ern = *reinterpret_cast<const float4*>(er + n * 4);

    const int ho = lane >> 4;
    const float eoa = (ho & 2) ? ern.z : ern.x;
    const float eob = (ho & 2) ? ern.w : ern.y;
    const float ero = (ho & 1) ? eob : eoa;

    const int q   = lane >> 4;
    const int cg  = lane & 15;
    const int hr  = cg >> 2;
    const int hsh = hr << 4;

    float a[8];
#pragma unroll
    for (int i = 0; i < 8; ++i) a[i] = 0.f;
    float ssum = 0.f;

    for (int base = 0; base < deg; base += 64) {
        int cnt = min(64, deg - base);
        int sr = 0;
        if (lane < cnt) sr = sorted_src[start + base + lane];

        float w[4];
#pragma unroll
        for (int k = 0; k < 4; ++k) {
            int ee = (lane & 15) + 16 * k;
            int sk = __shfl(sr, ee);
            float v = el[sk * 4 + ho] + ero;
            v = (v >= 0.f) ? v : 0.2f * v;
            w[k] = (ee < cnt) ? __expf(v) : 0.f;
        }

#pragma unroll
        for (int k = 0; k < 4; ++k) {
            int rem = cnt - 16 * k;
            if (rem > 0) {
                int quads = (min(rem, 16) + 3) >> 2;
#pragma unroll 4
                for (int it = 0; it < quads; ++it) {
                    int e0 = 16 * k + 4 * it + q;
                    int   se = __shfl(sr, e0);
                    float we = __shfl(w[k], (4 * it + q) | hsh);
                    uint4 raw = hh16[(long long)se * 16 + cg];
                    union { uint4 u; __half2 h[4]; } cv; cv.u = raw;
                    float2 v0 = __half22float2(cv.h[0]);
                    float2 v1 = __half22float2(cv.h[1]);
                    float2 v2 = __half22float2(cv.h[2]);
                    float2 v3 = __half22float2(cv.h[3]);
                    a[0] += we * v0.x; a[1] += we * v0.y;
                    a[2] += we * v1.x; a[3] += we * v1.y;
                    a[4] += we * v2.x; a[5] += we * v2.y;
                    a[6] += we * v3.x; a[7] += we * v3.y;
                    ssum += we;
                }
            }
        }
    }

#pragma unroll
    for (int i = 0; i < 8; ++i) {
        a[i] += __shfl_xor(a[i], 16);
        a[i] += __shfl_xor(a[i], 32);
    }
    ssum += __shfl_xor(ssum, 16);
    ssum += __shfl_xor(ssum, 32);

    if (lane < 16) {
        float inv = (ssum > 0.f) ? 1.f / ssum : 0.f;
        int c0 = cg * 8;
        float4 b0 = *reinterpret_cast<const float4*>(bias + c0);
        float4 b1 = *reinterpret_cast<const float4*>(bias + c0 + 4);
        float o0 = fmaxf(a[0] * inv + b0.x, 0.f);
        float o1 = fmaxf(a[1] * inv + b0.y, 0.f);
        float o2 = fmaxf(a[2] * inv + b0.z, 0.f);
        float o3 = fmaxf(a[3] * inv + b0.w, 0.f);
        float o4 = fmaxf(a[4] * inv + b1.x, 0.f);
        float o5 = fmaxf(a[5] * inv + b1.y, 0.f);
        float o6 = fmaxf(a[6] * inv + b1.z, 0.f);
        float o7 = fmaxf(a[7] * inv + b1.w, 0.f);
        union { uint4 u; __half2 h[4]; } pk;
        pk.h[0] = __floats2half2_rn(o0, o1);
        pk.h[1] = __floats2half2_rn(o2, o3);
        pk.h[2] = __floats2half2_rn(o4, o5);
        pk.h[3] = __floats2half2_rn(o6, o7);
        *reinterpret_cast<uint4*>(out + (long long)n * 128 + c0) = pk.u;
    }
}

// ---- single-head (F=64), fp16 h, 8 edges/iter (16B loads), f32 out ----
__global__ __launch_bounds__(256)
void gat_agg_h1(const int* __restrict__ row_ptr, const int* __restrict__ sorted_src,
                const float* __restrict__ el, const float* __restrict__ er,
                const __half* __restrict__ hh, const float* __restrict__ bias,
                float* __restrict__ out) {
    const uint4* hh16 = reinterpret_cast<const uint4*>(hh);   // row = 8 x 16B
    const int lane = threadIdx.x & 63;
    const int wid  = threadIdx.x >> 6;
    const int n    = blockIdx.x * 4 + wid;
    if (n >= N_NODES) return;

    const int start = row_ptr[n];
    const int deg   = row_ptr[n + 1] - start;
    const float ern = er[n];

    const int q  = lane >> 3;           // edge slot 0..7
    const int cg = lane & 7;            // cols cg*8..cg*8+7

    float a[8];
#pragma unroll
    for (int i = 0; i < 8; ++i) a[i] = 0.f;
    float ssum = 0.f;

    for (int base = 0; base < deg; base += 64) {
        int cnt = min(64, deg - base);
        int sr = 0;
        float w = 0.f;
        if (lane < cnt) {
            sr = sorted_src[start + base + lane];
            float v = el[sr] + ern;
            v = (v >= 0.f) ? v : 0.2f * v;
            w = __expf(v);
        }
        int octs = (cnt + 7) >> 3;
#pragma unroll 2
        for (int it = 0; it < octs; ++it) {
            int e0 = 8 * it + q;
            int   se = __shfl(sr, e0);
            float we = __shfl(w, e0);
            uint4 raw = hh16[(long long)se * 8 + cg];
            union { uint4 u; __half2 h[4]; } cv; cv.u = raw;
            float2 v0 = __half22float2(cv.h[0]);
            float2 v1 = __half22float2(cv.h[1]);
            float2 v2 = __half22float2(cv.h[2]);
            float2 v3 = __half22float2(cv.h[3]);
            a[0] += we * v0.x; a[1] += we * v0.y;
            a[2] += we * v1.x; a[3] += we * v1.y;
            a[4] += we * v2.x; a[5] += we * v2.y;
            a[6] += we * v3.x; a[7] += we * v3.y;
            ssum += we;
        }
    }

#pragma unroll
    for (int i = 0; i < 8; ++i) {
        a[i] += __shfl_xor(a[i], 8);
        a[i] += __shfl_xor(a[i], 16);
        a[i] += __shfl_xor(a[i], 32);
    }
    ssum += __shfl_xor(ssum, 8);
    ssum += __shfl_xor(ssum, 16);
    ssum += __shfl_xor(ssum, 32);

    if (lane < 8) {
        float inv = (ssum > 0.f) ? 1.f / ssum : 0.f;
        int c0 = cg * 8;
        float4 b0 = *reinterpret_cast<const float4*>(bias + c0);
        float4 b1 = *reinterpret_cast<const float4*>(bias + c0 + 4);
        float4 oA = make_float4(a[0] * inv + b0.x, a[1] * inv + b0.y,
                                a[2] * inv + b0.z, a[3] * inv + b0.w);
        float4 oB = make_float4(a[4] * inv + b1.x, a[5] * inv + b1.y,
                                a[6] * inv + b1.z, a[7] * inv + b1.w);
        *reinterpret_cast<float4*>(out + (long long)n * 64 + c0)     = oA;
        *reinterpret_cast<float4*>(out + (long long)n * 64 + c0 + 4) = oB;
    }
}

extern "C" void kernel_launch(void* const* d_in, const int* in_sizes, int n_in,
                              void* d_out, int out_size, void* d_ws, size_t ws_size,
                              hipStream_t stream) {
    const float* feat = (const float*)d_in[0];
    const int*   src  = (const int*)d_in[1];
    const int*   dst  = (const int*)d_in[2];
    const float* W1  = (const float*)d_in[3];
    const float* al1 = (const float*)d_in[4];
    const float* ar1 = (const float*)d_in[5];
    const float* b1  = (const float*)d_in[6];
    const float* W2  = (const float*)d_in[7];
    const float* al2 = (const float*)d_in[8];
    const float* ar2 = (const float*)d_in[9];
    const float* b2  = (const float*)d_in[10];
    const float* W3  = (const float*)d_in[11];
    const float* al3 = (const float*)d_in[12];
    const float* ar3 = (const float*)d_in[13];
    const float* b3  = (const float*)d_in[14];

    // workspace carve-up (offsets in f32 units on the base pointer)
    float* ws = (float*)d_ws;
    __half* xh2 = (__half*)ws;                              // N*128 halves = N*64 f32
    __half* hh  = (__half*)(ws + (long long)N_NODES * 64);  // N*128 halves
    float* el   = ws + (long long)N_NODES * 128;            // N*4
    float* er   = el + (long long)N_NODES * 4;              // N*4
    __half* wt1 = (__half*)(er + (long long)N_NODES * 4);   // 32768 halves
    __half* wt2 = wt1 + 32768;                              // 16384 halves
    __half* wt3 = wt2 + 16384;                              // 8192 halves
    int* counts     = (int*)(wt3 + 8192);                   // N
    int* row_ptr    = counts  + N_NODES;                    // N+1
    int* pbh        = row_ptr + N_NODES + 1;                // NBUK*NAB
    int* bsum       = pbh + NBUK * NAB;                     // 64
    int* sorted_src = bsum + 64;                            // E
    unsigned* binned = (unsigned*)(sorted_src + N_EDGES);   // E

    // ---- CSR build: hist -> scan -> 2-level partition ----
    const int SB = (N_NODES + 1023) / 1024;   // 49
    zero_counts<<<(N_NODES + 255) / 256, 256, 0, stream>>>(counts);
    hist_kernel<<<(N_EDGES + 255) / 256, 256, 0, stream>>>(dst, counts);
    scan_local<<<SB, 1024, 0, stream>>>(counts, row_ptr, bsum);
    scan_bsums<<<1, 64, 0, stream>>>(bsum, row_ptr, SB);
    scan_add<<<(N_NODES + 255) / 256, 256, 0, stream>>>(row_ptr, bsum);
    part_hist<<<NAB, 256, 0, stream>>>(dst, pbh);
    part_scan<<<NBUK, 512, 0, stream>>>(row_ptr, pbh);
    part_scatter<<<NAB, 256, 0, stream>>>(src, dst, pbh, binned);
    part_fin<<<NBUK, 256, 0, stream>>>(row_ptr, binned, sorted_src);

    // all weight transposes in one launch
    wtrans_all<<<(57344 + 255) / 256, 256, 0, stream>>>(W1, W2, W3, wt1, wt2, wt3);

    const int gblocks = (N_NODES + 63) / 64;   // 782
    const int nblocks = (N_NODES + 3) / 4;

    // ---- layer 1: 256 -> 4x32, relu (A read directly as f32) ----
    gemm_mfma<128, 256, true><<<gblocks, 256, 0, stream>>>(feat, wt1, hh, al1, ar1, el, er);
    gat_agg_h4<<<nblocks, 256, 0, stream>>>(row_ptr, sorted_src, el, er, hh, b1, xh2);

    // ---- layer 2: 128 -> 4x32, relu ----
    gemm_mfma<128, 128, false><<<gblocks, 256, 0, stream>>>(xh2, wt2, hh, al2, ar2, el, er);
    gat_agg_h4<<<nblocks, 256, 0, stream>>>(row_ptr, sorted_src, el, er, hh, b2, xh2);

    // ---- layer 3: 128 -> 1x64, no relu, f32 to d_out ----
    gemm_mfma<64, 128, false><<<gblocks, 256, 0, stream>>>(xh2, wt3, hh, al3, ar3, el, er);
    gat_agg_h1<<<nblocks, 256, 0, stream>>>(row_ptr, sorted_src, el, er, hh, b3, (float*)d_out);
}

// Round 17
// 188.847 us; speedup vs baseline: 1.2642x; 1.2217x over previous
//
#include <hip/hip_runtime.h>
#include <hip/hip_fp16.h>
#include <cfloat>

#define N_NODES 50000
#define N_EDGES 800000
#define NBUK 196          // ceil(N/256) dst-buckets of 256 nodes
#define NAB 512           // A-blocks for the partition
#define EPB 1563          // edges per A-block (512*1563 >= 800000)

typedef _Float16 half8 __attribute__((ext_vector_type(8)));
typedef float f32x4 __attribute__((ext_vector_type(4)));

// All three W[K][BN] f32 -> Wt[BN][K] fp16, one launch
__global__ void wtrans_all(const float* __restrict__ W1, const float* __restrict__ W2,
                           const float* __restrict__ W3, __half* __restrict__ wt1,
                           __half* __restrict__ wt2, __half* __restrict__ wt3) {
    int i = blockIdx.x * blockDim.x + threadIdx.x;
    if (i < 32768) {
        int n = i / 256, k = i % 256;
        wt1[i] = __float2half(W1[k * 128 + n]);
    } else if (i < 32768 + 16384) {
        int j = i - 32768;
        int n = j / 128, k = j % 128;
        wt2[j] = __float2half(W2[k * 128 + n]);
    } else if (i < 32768 + 16384 + 8192) {
        int j = i - 32768 - 16384;
        int n = j / 128, k = j % 128;
        wt3[j] = __float2half(W3[k * 64 + n]);
    }
}

// ============================================================================
// MFMA GEMM: h[N,BN] = x[N,K] @ W (via Wt[BN][K]), fp16 out, f32 acc.
// AF32: A is f32 (converted to fp16 in staging registers) else fp16.
// BM=64, BK=64, 4 waves x 16-row strips. Fused el/er epilogue.
// ============================================================================
template <int BN, int K, bool AF32>
__global__ __launch_bounds__(256)
void gemm_mfma(const void* __restrict__ xin, const __half* __restrict__ wt,
               __half* __restrict__ hh, const float* __restrict__ al,
               const float* __restrict__ ar, float* __restrict__ el,
               float* __restrict__ er) {
    constexpr int BM = 64, BK = 64;
    constexpr int LDA = BK + 8;
    constexpr int NT = BN / 16;
    constexpr int NH = (BN == 128) ? 4 : 1;
    constexpr int TPH = NT / NH;
    __shared__ __align__(16) _Float16 As[BM][LDA];
    __shared__ __align__(16) _Float16 Bs[BN][LDA];

    const __half* xh = (const __half*)xin;
    const float*  xf = (const float*)xin;

    const int t    = threadIdx.x;
    const int lane = t & 63;
    const int w    = t >> 6;
    const int r0   = blockIdx.x * BM;
    const int l15  = lane & 15;
    const int g    = lane >> 4;

    f32x4 acc[NT];
#pragma unroll
    for (int ct = 0; ct < NT; ++ct) acc[ct] = (f32x4){0.f, 0.f, 0.f, 0.f};

    const int arow = t >> 2;
    const int aseg = t & 3;
    const bool aok = (r0 + arow) < N_NODES;
    const int brow = t >> 1;
    const int bseg = t & 1;

    for (int k0 = 0; k0 < K; k0 += BK) {
#pragma unroll
        for (int s = 0; s < 2; ++s) {
            int seg = aseg + 4 * s;
            uint4 v = make_uint4(0, 0, 0, 0);
            if constexpr (AF32) {
                if (aok) {
                    const float* p = xf + (long long)(r0 + arow) * K + k0 + seg * 8;
                    float4 f0 = *reinterpret_cast<const float4*>(p);
                    float4 f1 = *reinterpret_cast<const float4*>(p + 4);
                    union { uint4 u; __half2 h[4]; } cv;
                    cv.h[0] = __floats2half2_rn(f0.x, f0.y);
                    cv.h[1] = __floats2half2_rn(f0.z, f0.w);
                    cv.h[2] = __floats2half2_rn(f1.x, f1.y);
                    cv.h[3] = __floats2half2_rn(f1.z, f1.w);
                    v = cv.u;
                }
            } else {
                if (aok) v = *reinterpret_cast<const uint4*>(xh + (long long)(r0 + arow) * K + k0 + seg * 8);
            }
            *reinterpret_cast<uint4*>(&As[arow][seg * 8]) = v;
        }
        if (brow < BN) {
#pragma unroll
            for (int s = 0; s < 4; ++s) {
                int seg = bseg + 2 * s;
                uint4 v = *reinterpret_cast<const uint4*>(wt + (long long)brow * K + k0 + seg * 8);
                *reinterpret_cast<uint4*>(&Bs[brow][seg * 8]) = v;
            }
        }
        __syncthreads();

#pragma unroll
        for (int kb = 0; kb < 2; ++kb) {
            half8 a = *reinterpret_cast<const half8*>(&As[w * 16 + l15][kb * 32 + g * 8]);
#pragma unroll
            for (int ct = 0; ct < NT; ++ct) {
                half8 b = *reinterpret_cast<const half8*>(&Bs[ct * 16 + l15][kb * 32 + g * 8]);
                acc[ct] = __builtin_amdgcn_mfma_f32_16x16x32_f16(a, b, acc[ct], 0, 0, 0);
            }
        }
        __syncthreads();
    }

    float alv[NT], arv[NT];
#pragma unroll
    for (int ct = 0; ct < NT; ++ct) {
        alv[ct] = al[ct * 16 + l15];
        arv[ct] = ar[ct * 16 + l15];
    }

    float pel[NH][4], per_[NH][4];
#pragma unroll
    for (int hd = 0; hd < NH; ++hd)
#pragma unroll
        for (int b = 0; b < 4; ++b) { pel[hd][b] = 0.f; per_[hd][b] = 0.f; }

#pragma unroll
    for (int ct = 0; ct < NT; ++ct) {
        int hd = ct / TPH;
#pragma unroll
        for (int b = 0; b < 4; ++b) {
            pel[hd][b] += acc[ct][b] * alv[ct];
            per_[hd][b] += acc[ct][b] * arv[ct];
        }
    }
#pragma unroll
    for (int off = 1; off < 16; off <<= 1) {
#pragma unroll
        for (int hd = 0; hd < NH; ++hd)
#pragma unroll
            for (int b = 0; b < 4; ++b) {
                pel[hd][b] += __shfl_xor(pel[hd][b], off);
                per_[hd][b] += __shfl_xor(per_[hd][b], off);
            }
    }

#pragma unroll
    for (int b = 0; b < 4; ++b) {
        int row = r0 + w * 16 + g * 4 + b;
        if (row >= N_NODES) continue;
#pragma unroll
        for (int ct = 0; ct < NT; ++ct)
            hh[(long long)row * BN + ct * 16 + l15] = __float2half(acc[ct][b]);
        if (l15 == 0) {
#pragma unroll
            for (int hd = 0; hd < NH; ++hd) {
                el[row * NH + hd] = pel[hd][b];
                er[row * NH + hd] = per_[hd][b];
            }
        }
    }
}

// ============================================================================
// CSR build — single-path bucket partition (no node-level histogram pipeline):
// P1 part_hist  : per (A-block, bucket) counts
// P2 part_scan  : per-bucket exclusive scan over A-blocks (seed 0) + totals
// P2b bucket_scan: exclusive scan of 196 bucket totals -> bstart
// P3 part_scatter: LDS-cursor scatter into bucket bins (seed bstart + local)
// P4 part_fin   : per-bucket LDS count + block scan -> row_ptr AND sorted_src
// ============================================================================
__global__ __launch_bounds__(256)
void part_hist(const int* __restrict__ dst, int* __restrict__ pbh) {
    __shared__ int cnt[NBUK];
    for (int i = threadIdx.x; i < NBUK; i += 256) cnt[i] = 0;
    __syncthreads();
    const int e0 = blockIdx.x * EPB, e1 = min(N_EDGES, e0 + EPB);
    for (int e = e0 + threadIdx.x; e < e1; e += 256)
        atomicAdd(&cnt[dst[e] >> 8], 1);
    __syncthreads();
    for (int i = threadIdx.x; i < NBUK; i += 256)
        pbh[i * NAB + blockIdx.x] = cnt[i];
}

__global__ __launch_bounds__(512)
void part_scan(int* __restrict__ pbh, int* __restrict__ btot) {
    __shared__ int wsums[8];
    const int b = blockIdx.x, t = threadIdx.x, lane = t & 63, wid = t >> 6;
    int v = pbh[b * NAB + t];
    int incl = v;
#pragma unroll
    for (int off = 1; off < 64; off <<= 1) {
        int s = __shfl_up(incl, off);
        if (lane >= off) incl += s;
    }
    if (lane == 63) wsums[wid] = incl;
    __syncthreads();
    if (wid == 0) {
        int ws = (lane < 8) ? wsums[lane] : 0;
#pragma unroll
        for (int off = 1; off < 8; off <<= 1) {
            int s = __shfl_up(ws, off);
            if (lane >= off) ws += s;
        }
        if (lane < 8) wsums[lane] = ws;
    }
    __syncthreads();
    int woff = (wid > 0) ? wsums[wid - 1] : 0;
    int excl = woff + incl - v;
    pbh[b * NAB + t] = excl;                       // local (within-bucket) offset
    if (t == NAB - 1) btot[b] = excl + v;          // bucket total
}

__global__ __launch_bounds__(256)
void bucket_scan(const int* __restrict__ btot, int* __restrict__ bstart) {
    __shared__ int wsums[4];
    const int t = threadIdx.x, lane = t & 63, wid = t >> 6;
    int v = (t < NBUK) ? btot[t] : 0;
    int incl = v;
#pragma unroll
    for (int off = 1; off < 64; off <<= 1) {
        int s = __shfl_up(incl, off);
        if (lane >= off) incl += s;
    }
    if (lane == 63) wsums[wid] = incl;
    __syncthreads();
    if (wid == 0) {
        int ws = (lane < 4) ? wsums[lane] : 0;
#pragma unroll
        for (int off = 1; off < 4; off <<= 1) {
            int s = __shfl_up(ws, off);
            if (lane >= off) ws += s;
        }
        if (lane < 4) wsums[lane] = ws;
    }
    __syncthreads();
    int woff = (wid > 0) ? wsums[wid - 1] : 0;
    if (t < NBUK) bstart[t] = woff + incl - v;
    if (t == 0) bstart[NBUK] = N_EDGES;
}

__global__ __launch_bounds__(256)
void part_scatter(const int* __restrict__ src, const int* __restrict__ dst,
                  const int* __restrict__ pbh, const int* __restrict__ bstart,
                  unsigned* __restrict__ binned) {
    __shared__ int cur[NBUK];
    for (int i = threadIdx.x; i < NBUK; i += 256)
        cur[i] = bstart[i] + pbh[i * NAB + blockIdx.x];
    __syncthreads();
    const int e0 = blockIdx.x * EPB, e1 = min(N_EDGES, e0 + EPB);
    for (int e = e0 + threadIdx.x; e < e1; e += 256) {
        int d = dst[e];
        int pos = atomicAdd(&cur[d >> 8], 1);
        binned[pos] = ((unsigned)src[e] << 8) | (unsigned)(d & 255);
    }
}

// P4: per-bucket node counts (LDS) -> block scan -> row_ptr + dense scatter
__global__ __launch_bounds__(256)
void part_fin(const int* __restrict__ bstart, const unsigned* __restrict__ binned,
              int* __restrict__ sorted_src, int* __restrict__ row_ptr) {
    __shared__ int cnt[256];
    __shared__ int wsums[4];
    const int b  = blockIdx.x;
    const int n0 = b * 256;
    const int t  = threadIdx.x, lane = t & 63, wid = t >> 6;
    const int e0 = bstart[b], e1 = bstart[b + 1];

    cnt[t] = 0;
    __syncthreads();
    for (int e = e0 + t; e < e1; e += 256)
        atomicAdd(&cnt[binned[e] & 255u], 1);
    __syncthreads();

    // 256-wide exclusive scan of cnt
    int v = cnt[t];
    int incl = v;
#pragma unroll
    for (int off = 1; off < 64; off <<= 1) {
        int s = __shfl_up(incl, off);
        if (lane >= off) incl += s;
    }
    if (lane == 63) wsums[wid] = incl;
    __syncthreads();
    if (wid == 0) {
        int ws = (lane < 4) ? wsums[lane] : 0;
#pragma unroll
        for (int off = 1; off < 4; off <<= 1) {
            int s = __shfl_up(ws, off);
            if (lane >= off) ws += s;
        }
        if (lane < 4) wsums[lane] = ws;
    }
    __syncthreads();
    int excl = ((wid > 0) ? wsums[wid - 1] : 0) + incl - v;

    if (n0 + t < N_NODES) row_ptr[n0 + t] = e0 + excl;
    if (b == NBUK - 1 && t == 0) row_ptr[N_NODES] = N_EDGES;

    __syncthreads();
    cnt[t] = e0 + excl;    // reuse as cursor
    __syncthreads();
    for (int e = e0 + t; e < e1; e += 256) {
        unsigned p = binned[e];
        int pos = atomicAdd(&cnt[p & 255u], 1);
        sorted_src[pos] = (int)(p >> 8);
    }
}

// ============================================================================
// Wave-per-node aggregate, 4 heads (F=128), fp16 h, no max pass, 4 edges/iter.
// ============================================================================
__global__ __launch_bounds__(256)
void gat_agg_h4(const int* __restrict__ row_ptr, const int* __restrict__ sorted_src,
                const float* __restrict__ el, const float* __restrict__ er,
                const __half* __restrict__ hh, const float* __restrict__ bias,
                __half* __restrict__ out) {
    const uint4* hh16 = reinterpret_cast<const uint4*>(hh);   // row = 16 x 16B
    const int lane = threadIdx.x & 63;
    const int wid  = threadIdx.x >> 6;
    const int n    = blockIdx.x * 4 + wid;
    if (n >= N_NODES) return;

    const int start = row_ptr[n];
    const int deg   = row_ptr[n + 1] - start;

    const float4 ern = *reinterpret_cast<const float4*>(er + n * 4);

    const int ho = lane >> 4;
    const float eoa = (ho & 2) ? ern.z : ern.x;
    const float eob = (ho & 2) ? ern.w : ern.y;
    const float ero = (ho & 1) ? eob : eoa;

    const int q   = lane >> 4;
    const int cg  = lane & 15;
    const int hr  = cg >> 2;
    const int hsh = hr << 4;

    float a[8];
#pragma unroll
    for (int i = 0; i < 8; ++i) a[i] = 0.f;
    float ssum = 0.f;

    for (int base = 0; base < deg; base += 64) {
        int cnt = min(64, deg - base);
        int sr = 0;
        if (lane < cnt) sr = sorted_src[start + base + lane];

        float w[4];
#pragma unroll
        for (int k = 0; k < 4; ++k) {
            int ee = (lane & 15) + 16 * k;
            int sk = __shfl(sr, ee);
            float v = el[sk * 4 + ho] + ero;
            v = (v >= 0.f) ? v : 0.2f * v;
            w[k] = (ee < cnt) ? __expf(v) : 0.f;
        }

#pragma unroll
        for (int k = 0; k < 4; ++k) {
            int rem = cnt - 16 * k;
            if (rem > 0) {
                int quads = (min(rem, 16) + 3) >> 2;
#pragma unroll 4
                for (int it = 0; it < quads; ++it) {
                    int e0 = 16 * k + 4 * it + q;
                    int   se = __shfl(sr, e0);
                    float we = __shfl(w[k], (4 * it + q) | hsh);
                    uint4 raw = hh16[(long long)se * 16 + cg];
                    union { uint4 u; __half2 h[4]; } cv; cv.u = raw;
                    float2 v0 = __half22float2(cv.h[0]);
                    float2 v1 = __half22float2(cv.h[1]);
                    float2 v2 = __half22float2(cv.h[2]);
                    float2 v3 = __half22float2(cv.h[3]);
                    a[0] += we * v0.x; a[1] += we * v0.y;
                    a[2] += we * v1.x; a[3] += we * v1.y;
                    a[4] += we * v2.x; a[5] += we * v2.y;
                    a[6] += we * v3.x; a[7] += we * v3.y;
                    ssum += we;
                }
            }
        }
    }

#pragma unroll
    for (int i = 0; i < 8; ++i) {
        a[i] += __shfl_xor(a[i], 16);
        a[i] += __shfl_xor(a[i], 32);
    }
    ssum += __shfl_xor(ssum, 16);
    ssum += __shfl_xor(ssum, 32);

    if (lane < 16) {
        float inv = (ssum > 0.f) ? 1.f / ssum : 0.f;
        int c0 = cg * 8;
        float4 b0 = *reinterpret_cast<const float4*>(bias + c0);
        float4 b1 = *reinterpret_cast<const float4*>(bias + c0 + 4);
        float o0 = fmaxf(a[0] * inv + b0.x, 0.f);
        float o1 = fmaxf(a[1] * inv + b0.y, 0.f);
        float o2 = fmaxf(a[2] * inv + b0.z, 0.f);
        float o3 = fmaxf(a[3] * inv + b0.w, 0.f);
        float o4 = fmaxf(a[4] * inv + b1.x, 0.f);
        float o5 = fmaxf(a[5] * inv + b1.y, 0.f);
        float o6 = fmaxf(a[6] * inv + b1.z, 0.f);
        float o7 = fmaxf(a[7] * inv + b1.w, 0.f);
        union { uint4 u; __half2 h[4]; } pk;
        pk.h[0] = __floats2half2_rn(o0, o1);
        pk.h[1] = __floats2half2_rn(o2, o3);
        pk.h[2] = __floats2half2_rn(o4, o5);
        pk.h[3] = __floats2half2_rn(o6, o7);
        *reinterpret_cast<uint4*>(out + (long long)n * 128 + c0) = pk.u;
    }
}

// ---- single-head (F=64), fp16 h, 8 edges/iter (16B loads), f32 out ----
__global__ __launch_bounds__(256)
void gat_agg_h1(const int* __restrict__ row_ptr, const int* __restrict__ sorted_src,
                const float* __restrict__ el, const float* __restrict__ er,
                const __half* __restrict__ hh, const float* __restrict__ bias,
                float* __restrict__ out) {
    const uint4* hh16 = reinterpret_cast<const uint4*>(hh);   // row = 8 x 16B
    const int lane = threadIdx.x & 63;
    const int wid  = threadIdx.x >> 6;
    const int n    = blockIdx.x * 4 + wid;
    if (n >= N_NODES) return;

    const int start = row_ptr[n];
    const int deg   = row_ptr[n + 1] - start;
    const float ern = er[n];

    const int q  = lane >> 3;           // edge slot 0..7
    const int cg = lane & 7;            // cols cg*8..cg*8+7

    float a[8];
#pragma unroll
    for (int i = 0; i < 8; ++i) a[i] = 0.f;
    float ssum = 0.f;

    for (int base = 0; base < deg; base += 64) {
        int cnt = min(64, deg - base);
        int sr = 0;
        float w = 0.f;
        if (lane < cnt) {
            sr = sorted_src[start + base + lane];
            float v = el[sr] + ern;
            v = (v >= 0.f) ? v : 0.2f * v;
            w = __expf(v);
        }
        int octs = (cnt + 7) >> 3;
#pragma unroll 2
        for (int it = 0; it < octs; ++it) {
            int e0 = 8 * it + q;
            int   se = __shfl(sr, e0);
            float we = __shfl(w, e0);
            uint4 raw = hh16[(long long)se * 8 + cg];
            union { uint4 u; __half2 h[4]; } cv; cv.u = raw;
            float2 v0 = __half22float2(cv.h[0]);
            float2 v1 = __half22float2(cv.h[1]);
            float2 v2 = __half22float2(cv.h[2]);
            float2 v3 = __half22float2(cv.h[3]);
            a[0] += we * v0.x; a[1] += we * v0.y;
            a[2] += we * v1.x; a[3] += we * v1.y;
            a[4] += we * v2.x; a[5] += we * v2.y;
            a[6] += we * v3.x; a[7] += we * v3.y;
            ssum += we;
        }
    }

#pragma unroll
    for (int i = 0; i < 8; ++i) {
        a[i] += __shfl_xor(a[i], 8);
        a[i] += __shfl_xor(a[i], 16);
        a[i] += __shfl_xor(a[i], 32);
    }
    ssum += __shfl_xor(ssum, 8);
    ssum += __shfl_xor(ssum, 16);
    ssum += __shfl_xor(ssum, 32);

    if (lane < 8) {
        float inv = (ssum > 0.f) ? 1.f / ssum : 0.f;
        int c0 = cg * 8;
        float4 b0 = *reinterpret_cast<const float4*>(bias + c0);
        float4 b1 = *reinterpret_cast<const float4*>(bias + c0 + 4);
        float4 oA = make_float4(a[0] * inv + b0.x, a[1] * inv + b0.y,
                                a[2] * inv + b0.z, a[3] * inv + b0.w);
        float4 oB = make_float4(a[4] * inv + b1.x, a[5] * inv + b1.y,
                                a[6] * inv + b1.z, a[7] * inv + b1.w);
        *reinterpret_cast<float4*>(out + (long long)n * 64 + c0)     = oA;
        *reinterpret_cast<float4*>(out + (long long)n * 64 + c0 + 4) = oB;
    }
}

extern "C" void kernel_launch(void* const* d_in, const int* in_sizes, int n_in,
                              void* d_out, int out_size, void* d_ws, size_t ws_size,
                              hipStream_t stream) {
    const float* feat = (const float*)d_in[0];
    const int*   src  = (const int*)d_in[1];
    const int*   dst  = (const int*)d_in[2];
    const float* W1  = (const float*)d_in[3];
    const float* al1 = (const float*)d_in[4];
    const float* ar1 = (const float*)d_in[5];
    const float* b1  = (const float*)d_in[6];
    const float* W2  = (const float*)d_in[7];
    const float* al2 = (const float*)d_in[8];
    const float* ar2 = (const float*)d_in[9];
    const float* b2  = (const float*)d_in[10];
    const float* W3  = (const float*)d_in[11];
    const float* al3 = (const float*)d_in[12];
    const float* ar3 = (const float*)d_in[13];
    const float* b3  = (const float*)d_in[14];

    // workspace carve-up (offsets in f32 units on the base pointer)
    float* ws = (float*)d_ws;
    __half* xh2 = (__half*)ws;                              // N*128 halves = N*64 f32
    __half* hh  = (__half*)(ws + (long long)N_NODES * 64);  // N*128 halves
    float* el   = ws + (long long)N_NODES * 128;            // N*4
    float* er   = el + (long long)N_NODES * 4;              // N*4
    __half* wt1 = (__half*)(er + (long long)N_NODES * 4);   // 32768 halves
    __half* wt2 = wt1 + 32768;                              // 16384 halves
    __half* wt3 = wt2 + 16384;                              // 8192 halves
    int* row_ptr    = (int*)(wt3 + 8192);                   // N+1
    int* pbh        = row_ptr + N_NODES + 1;                // NBUK*NAB
    int* btot       = pbh + NBUK * NAB;                     // NBUK
    int* bstart     = btot + NBUK;                          // NBUK+1
    int* sorted_src = bstart + NBUK + 1;                    // E
    unsigned* binned = (unsigned*)(sorted_src + N_EDGES);   // E

    // ---- CSR build: single-path bucket partition ----
    part_hist<<<NAB, 256, 0, stream>>>(dst, pbh);
    part_scan<<<NBUK, 512, 0, stream>>>(pbh, btot);
    bucket_scan<<<1, 256, 0, stream>>>(btot, bstart);
    part_scatter<<<NAB, 256, 0, stream>>>(src, dst, pbh, bstart, binned);
    part_fin<<<NBUK, 256, 0, stream>>>(bstart, binned, sorted_src, row_ptr);

    // all weight transposes in one launch
    wtrans_all<<<(57344 + 255) / 256, 256, 0, stream>>>(W1, W2, W3, wt1, wt2, wt3);

    const int gblocks = (N_NODES + 63) / 64;   // 782
    const int nblocks = (N_NODES + 3) / 4;

    // ---- layer 1: 256 -> 4x32, relu (A read directly as f32) ----
    gemm_mfma<128, 256, true><<<gblocks, 256, 0, stream>>>(feat, wt1, hh, al1, ar1, el, er);
    gat_agg_h4<<<nblocks, 256, 0, stream>>>(row_ptr, sorted_src, el, er, hh, b1, xh2);

    // ---- layer 2: 128 -> 4x32, relu ----
    gemm_mfma<128, 128, false><<<gblocks, 256, 0, stream>>>(xh2, wt2, hh, al2, ar2, el, er);
    gat_agg_h4<<<nblocks, 256, 0, stream>>>(row_ptr, sorted_src, el, er, hh, b2, xh2);

    // ---- layer 3: 128 -> 1x64, no relu, f32 to d_out ----
    gemm_mfma<64, 128, false><<<gblocks, 256, 0, stream>>>(xh2, wt3, hh, al3, ar3, el, er);
    gat_agg_h1<<<nblocks, 256, 0, stream>>>(row_ptr, sorted_src, el, er, hh, b3, (float*)d_out);
}